// Round 3
// baseline (63.870 us; speedup 1.0000x reference)
//
#include <hip/hip_runtime.h>

#define BB   8
#define CC   1024
#define NN   4096
#define KL   32
#define KK   1024
#define XMINF (-15.0f)
#define SPANF 30.0f
#define EPSF  1e-6f
#define ACC_SCALE 1048576.0f       // 2^20 fixed point for feature accum
#define ACC_INV   (1.0f/1048576.0f)
#define WS_SCALE  33554432.0f      // 2^25 fixed point for weight sums
#define WS_INV    (1.0f/33554432.0f)

// ---------------- Phase 1: bucket/CSR build + wsum + weights output ----------
// One block per batch. Every pixel lands in exactly one bucket = its base cell
// (cx0, cy0), both in [0,30] for in-range coords; its 2x2 bilinear footprint is
// expanded at gather time. All atomics are native u32.
__global__ __launch_bounds__(256) void WLP_build_kernel(
    const float2*   __restrict__ coord,      // (B, N)
    unsigned*       __restrict__ entries_g,  // (B, N) packed pix|qx|qy
    unsigned*       __restrict__ offs_g,     // (B, 1025)
    unsigned short* __restrict__ startbid_g, // (B, 256)
    float*          __restrict__ wsum_g,     // (B, KK)
    float*          __restrict__ weights_out)// (B, 16, KK)
{
  const int b = blockIdx.x, tid = threadIdx.x;
  __shared__ unsigned cnt[KK];
  __shared__ unsigned offl[KK];
  __shared__ unsigned wsl[KK];
  __shared__ unsigned wave_tot[4];
  for (int i = tid; i < KK; i += 256) { cnt[i] = 0u; wsl[i] = 0u; }
  __syncthreads();

  unsigned bkt[16]; unsigned pk[16];
  #pragma unroll
  for (int it = 0; it < 16; ++it) {
    int n = it * 256 + tid;
    float2 c = coord[(b << 12) + n];
    float gx = (c.x - XMINF) * (31.0f / SPANF);
    float gy = (c.y - XMINF) * (31.0f / SPANF);
    int cx = (int)floorf(gx); cx = min(max(cx, 0), 30);
    int cy = (int)floorf(gy); cy = min(max(cy, 0), 30);
    float wx = gx - (float)cx, wy = gy - (float)cy;
    int qx = __float2int_rn(wx * 1023.0f); qx = min(max(qx, 0), 1023);
    int qy = __float2int_rn(wy * 1023.0f); qy = min(max(qy, 0), 1023);
    unsigned bu = (unsigned)(cy * KL + cx);
    bkt[it] = bu;
    pk[it]  = (unsigned)n | ((unsigned)qx << 12) | ((unsigned)qy << 22);
    atomicAdd(&cnt[bu], 1u);
    float dx = (float)qx * (1.0f/1023.0f), dy = (float)qy * (1.0f/1023.0f);
    float ex = 1.0f - dx, ey = 1.0f - dy;
    atomicAdd(&wsl[bu],          (unsigned)__float2int_rn(ex*ey*WS_SCALE));
    atomicAdd(&wsl[bu+1],        (unsigned)__float2int_rn(dx*ey*WS_SCALE));
    atomicAdd(&wsl[bu+KL],       (unsigned)__float2int_rn(ex*dy*WS_SCALE));
    atomicAdd(&wsl[bu+KL+1],     (unsigned)__float2int_rn(dx*dy*WS_SCALE));
  }
  __syncthreads();

  // exclusive scan of cnt[1024] -> offl[1024]
  uint4 c4 = ((const uint4*)cnt)[tid];
  unsigned tsum = c4.x + c4.y + c4.z + c4.w;
  int lane = tid & 63, wid = tid >> 6;
  unsigned v = tsum;
  #pragma unroll
  for (int d = 1; d < 64; d <<= 1) { unsigned u = __shfl_up(v, d, 64); if (lane >= d) v += u; }
  if (lane == 63) wave_tot[wid] = v;
  unsigned wexcl = v - tsum;
  __syncthreads();
  unsigned base = wexcl;
  for (int w = 0; w < wid; ++w) base += wave_tot[w];
  offl[4*tid]   = base;
  offl[4*tid+1] = base + c4.x;
  offl[4*tid+2] = base + c4.x + c4.y;
  offl[4*tid+3] = base + c4.x + c4.y + c4.z;
  __syncthreads();

  #pragma unroll
  for (int i = 0; i < 4; ++i) offs_g[b*1025 + 4*tid + i] = offl[4*tid + i];
  if (tid == 0) offs_g[b*1025 + 1024] = NN;

  // per-thread start bucket for phase 2 (entry range [16*tid, 16*tid+16))
  {
    int target = tid * 16, bid = 0;
    #pragma unroll
    for (int s = 512; s > 0; s >>= 1) {
      int cand = bid + s;
      if (cand <= 1023 && (int)offl[cand] <= target) bid = cand;
    }
    startbid_g[(b << 8) + tid] = (unsigned short)bid;
  }

  // cursor = copy of offsets (cnt reused), then scatter entries into slots
  for (int i = tid; i < KK; i += 256) cnt[i] = offl[i];
  __syncthreads();
  #pragma unroll
  for (int it = 0; it < 16; ++it) {
    unsigned slot = atomicAdd(&cnt[bkt[it]], 1u);
    entries_g[(b << 12) + slot] = pk[it];
  }

  // wsum + broadcast weights output
  for (int i = tid; i < KK; i += 256) {
    float s = (float)wsl[i] * WS_INV;
    wsum_g[(b << 10) + i] = s;
    #pragma unroll
    for (int t = 0; t < 16; ++t)
      weights_out[((size_t)(b * 16 + t) << 10) + i] = s;
  }
}

// ---------------- Phase 2: per-(b, channel-PAIR) gather --------------------
// G=2 channels per block. Rows staged interleaved [pix][2] so one b64 LDS
// read serves both channels; entry decode + bucket walk amortized 2x.
__global__ __launch_bounds__(256) void WLP_gather_kernel(
    const float*          __restrict__ feats,      // (B, CC, NN)
    const unsigned*       __restrict__ entries_g,
    const unsigned*       __restrict__ offs_g,
    const unsigned short* __restrict__ startbid_g,
    const float*          __restrict__ wsum_g,
    float*                __restrict__ world)      // (B, CC, KK)
{
  const int bg  = blockIdx.x;          // b * 512 + pair
  const int b   = bg >> 9;
  const int c0  = (bg & 511) << 1;
  const int tid = threadIdx.x;

  __shared__ float          rows[NN * 2];    // [pix][2]  32 KB
  __shared__ unsigned short off_l[KK + 2];   // 2 KB
  __shared__ int            acc[2 * KK];     // [ch][cell] 8 KB

  // stage both rows, interleaving channels per pixel (conflict-free b128s)
  const float4* f0 = (const float4*)(feats + (((size_t)(b << 10) + c0) << 12));
  const float4* f1 = f0 + 1024;              // next channel (4096 floats)
  #pragma unroll
  for (int k = 0; k < 4; ++k) {
    int p4 = k * 256 + tid;                  // pixels 4*p4 .. 4*p4+3
    float4 a = f0[p4], c = f1[p4];
    float4* dst = (float4*)&rows[p4 << 3];
    dst[0] = make_float4(a.x, c.x, a.y, c.y);
    dst[1] = make_float4(a.z, c.z, a.w, c.w);
  }
  for (int i = tid; i < KK + 1; i += 256) off_l[i] = (unsigned short)offs_g[b * 1025 + i];
  #pragma unroll
  for (int k = 0; k < 8; ++k) acc[k * 256 + tid] = 0;

  const uint4* eb = (const uint4*)(entries_g + (b << 12));
  uint4 e0 = eb[4*tid], e1 = eb[4*tid+1], e2v = eb[4*tid+2], e3 = eb[4*tid+3];
  int bid = startbid_g[(b << 8) + tid];
  __syncthreads();

  int nxt = off_l[bid + 1];
  float a00=0.f, a10=0.f, a01=0.f, a11=0.f;   // channel c0
  float c00=0.f, c10=0.f, c01=0.f, c11=0.f;   // channel c0+1
  bool dirty = false;
  int e = tid * 16;

  #define FLUSH() { \
    atomicAdd(&acc[bid],           __float2int_rn(a00 * ACC_SCALE)); \
    atomicAdd(&acc[bid+1],         __float2int_rn(a10 * ACC_SCALE)); \
    atomicAdd(&acc[bid+KL],        __float2int_rn(a01 * ACC_SCALE)); \
    atomicAdd(&acc[bid+KL+1],      __float2int_rn(a11 * ACC_SCALE)); \
    atomicAdd(&acc[KK+bid],        __float2int_rn(c00 * ACC_SCALE)); \
    atomicAdd(&acc[KK+bid+1],      __float2int_rn(c10 * ACC_SCALE)); \
    atomicAdd(&acc[KK+bid+KL],     __float2int_rn(c01 * ACC_SCALE)); \
    atomicAdd(&acc[KK+bid+KL+1],   __float2int_rn(c11 * ACC_SCALE)); \
    a00=a10=a01=a11=0.f; c00=c10=c01=c11=0.f; dirty = false; }

  #define PROC(u) { \
    while (e >= nxt) { if (dirty) FLUSH(); ++bid; nxt = off_l[bid + 1]; } \
    float fx = (float)((u >> 12) & 1023u) * (1.0f/1023.0f); \
    float fy = (float)(u >> 22) * (1.0f/1023.0f); \
    int   p  = (int)(u & 4095u); \
    float2 v = *(const float2*)&rows[p << 1]; \
    float ex = 1.0f - fx, ey = 1.0f - fy; \
    float w00 = ex*ey, w10 = fx*ey, w01 = ex*fy, w11 = fx*fy; \
    a00 += w00*v.x; a10 += w10*v.x; a01 += w01*v.x; a11 += w11*v.x; \
    c00 += w00*v.y; c10 += w10*v.y; c01 += w01*v.y; c11 += w11*v.y; \
    dirty = true; ++e; }

  PROC(e0.x) PROC(e0.y) PROC(e0.z) PROC(e0.w)
  PROC(e1.x) PROC(e1.y) PROC(e1.z) PROC(e1.w)
  PROC(e2v.x) PROC(e2v.y) PROC(e2v.z) PROC(e2v.w)
  PROC(e3.x) PROC(e3.y) PROC(e3.z) PROC(e3.w)
  if (dirty) FLUSH();
  #undef PROC
  #undef FLUSH
  __syncthreads();

  const size_t ob = ((size_t)(b << 10) + c0) << 10;
  #pragma unroll
  for (int k = 0; k < 4; ++k) {
    int cell = k * 256 + tid;
    float s = fmaxf(wsum_g[(b << 10) + cell], EPSF);
    world[ob + cell]      = (float)acc[cell]      * ACC_INV / s;
    world[ob + KK + cell] = (float)acc[KK + cell] * ACC_INV / s;
  }
}

extern "C" void kernel_launch(void* const* d_in, const int* in_sizes, int n_in,
                              void* d_out, int out_size, void* d_ws, size_t ws_size,
                              hipStream_t stream) {
  const float*  feats = (const float*)d_in[0];   // (B,T,D,HP,WP) = (B,1024,4096)
  const float2* coord = (const float2*)d_in[1];  // (B,HP,WP) float2
  float* out = (float*)d_out;
  float* world       = out;                          // B*CC*KK
  float* weights_out = out + (size_t)BB * CC * KK;   // B*16*KK

  unsigned*       entries_g  = (unsigned*)d_ws;                       // 8*4096 u32
  unsigned*       offs_g     = entries_g + BB * NN;                   // 8*1025 u32
  float*          wsum_g     = (float*)(offs_g + BB * 1025);          // 8*1024 f32
  unsigned short* startbid_g = (unsigned short*)(wsum_g + BB * KK);   // 8*256 u16

  WLP_build_kernel<<<BB, 256, 0, stream>>>(coord, entries_g, offs_g, startbid_g,
                                           wsum_g, weights_out);
  WLP_gather_kernel<<<BB * CC / 2, 256, 0, stream>>>(feats, entries_g, offs_g,
                                                     startbid_g, wsum_g, world);
}